// Round 17
// baseline (2595.796 us; speedup 1.0000x reference)
//
#include <hip/hip_runtime.h>
#include <hip/hip_bf16.h>
#include <hip/hip_fp8.h>
#include <stdint.h>

typedef __hip_bfloat16 bf16_t;
typedef __attribute__((ext_vector_type(8))) short bf16x8;
typedef __attribute__((ext_vector_type(4))) float f32x4;

#define MU_DT 0.01f
#define S8 8.0f                  // fp8 operand pre-scale (escape subnormals)
#define INV_S64 (1.0f / 64.0f)   // descale after fp8xfp8 GEMM

__device__ inline uint8_t f2fp8(float x) {
  __hip_fp8_e4m3 t(x);           // OCP e4m3 on gfx950
  return t.__x;
}

__device__ inline void gload_lds16(const void* g, void* lds) {
  __builtin_amdgcn_global_load_lds((const __attribute__((address_space(1))) void*)g,
                                   (__attribute__((address_space(3))) void*)lds, 16, 0, 0);
}

struct Seg { int start, layer, tmBase, tilesN; };

// ======================= fp8 iteration kernel =======================
// R17: BM=BN=128, BK=128, SIXTEEN waves (1024 thr), per-wave 32x32 —
// the per-wave engine is byte-identical to R16's proven fp8 kernel; only
// block geometry doubled. Staged bytes ~ M*N*K*(1/BM+1/BN): 128^2 cuts
// them 33% vs 64x128. R12's 128^2 failure was 8-wave blocks (6.4 waves/CU);
// 16-wave blocks give 32 waves/CU on doubled CUs (LDS 64KiB -> 2 blk/CU).
// Makespan (round-robin id->CU model, validated R15): fwd 40 steps
// (doubles L2+L0), bwd 48 (doubles L2+L2) vs R16's 64/72.
struct GemmLayer8 {
  const uint8_t* A;    // (512 x K) fp8(x8), row-major
  const uint8_t* Bt;   // (N x K) fp8(x8), row-major
  const float*  X;     // fwd: mu_{l+1}/img (f32); bwd: mu_l (f32)
  const float*  E;     // bwd l>0: e_l
  float*        O1;    // fwd: e out; bwd: mu out (f32 master)
  uint8_t*      O2a;   // fwd: G8 out; bwd: m8 out (fp8 x8)
  bf16_t*       O2b;   // bwd: mb out (bf16, for final pass)
  int K, N, mode;
};
struct GemmArgs8 { GemmLayer8 L[3]; Seg seg[8]; };

__global__ __launch_bounds__(1024) void gemm_fp8(GemmArgs8 args) {
  __shared__ __align__(16) uint8_t As[2 * 128 * 128];   // 2 x 16 KiB
  __shared__ __align__(16) uint8_t Bs[2 * 128 * 128];   // 2 x 16 KiB

  const int bid = blockIdx.x;
  int s = 0;
#pragma unroll
  for (int i = 1; i < 8; ++i)
    if (bid >= args.seg[i].start) s = i;
  const Seg sg = args.seg[s];
  const GemmLayer8 Lr = args.L[sg.layer];
  const int local = bid - sg.start;
  const int tm = sg.tmBase + local / sg.tilesN;
  const int tn = local % sg.tilesN;
  const int K = Lr.K;
  const int rowBase = tm * 128;
  const int colBase = tn * 128;

  const int tid  = threadIdx.x;        // 0..1023
  const int lane = tid & 63;
  const int wv   = tid >> 6;           // 0..15
  const int wrM  = wv >> 2;            // 0..3 -> 32-row band
  const int wcN  = wv & 3;             // 0..3 -> 32-col band
  const int lo   = lane & 15, hi = lane >> 4;

  f32x4 acc[2][2];
#pragma unroll
  for (int m = 0; m < 2; ++m)
#pragma unroll
    for (int n = 0; n < 2; ++n)
      acc[m][n] = f32x4{0.f, 0.f, 0.f, 0.f};

  char* AsB = (char*)As;   // halves at +0 / +16384
  char* BsB = (char*)Bs;   // halves at +0 / +16384

  // staging: tile 128 rows x 128 B = 1024 chunks, 1 per thread.
  // chunk c -> row = c>>3, slot = c&7; swizzle slot ^= row&7 on SOURCE.
  const uint8_t* pA0;
  const uint8_t* pB0;
  {
    const int c = tid;
    const int r = c >> 3, sw = (c & 7) ^ (r & 7);
    pA0 = Lr.A  + (size_t)(rowBase + r) * K + sw * 16;
    pB0 = Lr.Bt + (size_t)(colBase + r) * K + sw * 16;
  }

  // read-side: frag (m|n, kk): k = kk*32 + hi*8
  int aoff[2][4], boff[2][4];
#pragma unroll
  for (int m = 0; m < 2; ++m) {
    const int row = wrM * 32 + m * 16 + lo;
#pragma unroll
    for (int kk = 0; kk < 4; ++kk)
      aoff[m][kk] = row * 128 + (((kk * 2 + (hi >> 1)) ^ (row & 7)) << 4) + ((hi & 1) << 3);
  }
#pragma unroll
  for (int n = 0; n < 2; ++n) {
    const int row = wcN * 32 + n * 16 + lo;
#pragma unroll
    for (int kk = 0; kk < 4; ++kk)
      boff[n][kk] = row * 128 + (((kk * 2 + (hi >> 1)) ^ (row & 7)) << 4) + ((hi & 1) << 3);
  }

  const int waveB = wv * 1024;
  const int nkt = K >> 7;   // BK=128; 8..32 steps

  gload_lds16(pA0, AsB + waveB);
  gload_lds16(pB0, BsB + waveB);
  __syncthreads();

  int cur = 0;
  for (int kt = 0; kt < nkt; ++kt) {
    const int curO = cur * 16384;
    if (kt + 1 < nkt) {
      const int ke = (kt + 1) * 128;
      gload_lds16(pA0 + ke, AsB + (curO ^ 16384) + waveB);
      gload_lds16(pB0 + ke, BsB + (curO ^ 16384) + waveB);
    }

    long a[2][4], b[2][4];
#pragma unroll
    for (int m = 0; m < 2; ++m)
#pragma unroll
      for (int kk = 0; kk < 4; ++kk)
        a[m][kk] = *(const long*)(AsB + curO + aoff[m][kk]);
#pragma unroll
    for (int n = 0; n < 2; ++n)
#pragma unroll
      for (int kk = 0; kk < 4; ++kk)
        b[n][kk] = *(const long*)(BsB + curO + boff[n][kk]);

#pragma unroll
    for (int kk = 0; kk < 4; ++kk)
#pragma unroll
      for (int m = 0; m < 2; ++m)
#pragma unroll
        for (int n = 0; n < 2; ++n)
          acc[m][n] = __builtin_amdgcn_mfma_f32_16x16x32_fp8_fp8(a[m][kk], b[n][kk], acc[m][n], 0, 0, 0);

    if (kt + 1 < nkt) {
      __syncthreads();
      cur ^= 1;
    }
  }

  // epilogue — C/D layout: col = lane&15, row = (lane>>4)*4 + reg
  const int N = Lr.N;
#pragma unroll
  for (int m = 0; m < 2; ++m) {
#pragma unroll
    for (int n = 0; n < 2; ++n) {
#pragma unroll
      for (int r = 0; r < 4; ++r) {
        const int row = rowBase + wrM * 32 + m * 16 + hi * 4 + r;
        const int col = colBase + wcN * 32 + n * 16 + lo;
        const float v = acc[m][n][r] * INV_S64;
        const size_t iN = (size_t)row * N + col;
        if (Lr.mode == 0) {
          const float mu = Lr.X[iN];
          const float t  = tanhf(v);
          const float e  = mu - t;
          Lr.O1[iN]  = e;
          Lr.O2a[iN] = f2fp8(e * (1.0f - t * t) * S8);
        } else if (Lr.mode == 1) {
          const float e = Lr.X[iN] - v;
          Lr.O1[iN]  = e;
          Lr.O2a[iN] = f2fp8(e * S8);
        } else {
          const float mu = Lr.X[iN];
          const float sub = (Lr.mode == 2) ? mu : Lr.E[iN];
          const float nv = mu + MU_DT * (v - sub);
          Lr.O1[iN]  = nv;
          Lr.O2a[iN] = f2fp8(nv * S8);
          Lr.O2b[iN] = __float2bfloat16(nv);
        }
      }
    }
  }
}

// ======================= bf16 final-pass kernel (R16 verbatim) =======================
struct GemmLayer {
  const bf16_t* A;
  const bf16_t* Bt;
  const float*  X;
  const float*  E;
  float*        O1;
  bf16_t*       O2;
  int K, N, ostride, mode;
};
struct GemmArgs { GemmLayer L[3]; Seg seg[8]; };

__global__ __launch_bounds__(512) void gemm_bf16(GemmArgs args) {
  __shared__ __align__(16) bf16_t As[2 * 64 * 64];
  __shared__ __align__(16) bf16_t Bs[2 * 128 * 64];

  const int bid = blockIdx.x;
  int s = 0;
#pragma unroll
  for (int i = 1; i < 8; ++i)
    if (bid >= args.seg[i].start) s = i;
  const Seg sg = args.seg[s];
  const GemmLayer Lr = args.L[sg.layer];
  const int local = bid - sg.start;
  const int tm = sg.tmBase + local / sg.tilesN;
  const int tn = local % sg.tilesN;
  const int K = Lr.K;
  const int rowBase = tm * 64;
  const int colBase = tn * 128;

  const int tid  = threadIdx.x;
  const int lane = tid & 63;
  const int wv   = tid >> 6;
  const int wrM  = wv >> 2;
  const int wcN  = wv & 3;
  const int lo   = lane & 15, hi = lane >> 4;

  f32x4 acc[2][2];
#pragma unroll
  for (int m = 0; m < 2; ++m)
#pragma unroll
    for (int n = 0; n < 2; ++n)
      acc[m][n] = f32x4{0.f, 0.f, 0.f, 0.f};

  char* AsB = (char*)As;
  char* BsB = (char*)Bs;

  const bf16_t* pA0;
  const bf16_t* pB[2];
  {
    const int c = tid;
    const int r = c >> 3, sw = (c & 7) ^ (r & 7);
    pA0 = Lr.A + (size_t)(rowBase + r) * K + sw * 8;
  }
#pragma unroll
  for (int j = 0; j < 2; ++j) {
    const int c = j * 512 + tid;
    const int r = c >> 3, sw = (c & 7) ^ (r & 7);
    pB[j] = Lr.Bt + (size_t)(colBase + r) * K + sw * 8;
  }

  int aoff[2][2], boff[2][2];
#pragma unroll
  for (int m = 0; m < 2; ++m) {
    const int row = wrM * 32 + m * 16 + lo;
#pragma unroll
    for (int kk = 0; kk < 2; ++kk)
      aoff[m][kk] = row * 128 + (((kk * 4 + hi) ^ (row & 7)) << 4);
  }
#pragma unroll
  for (int n = 0; n < 2; ++n) {
    const int row = wcN * 32 + n * 16 + lo;
#pragma unroll
    for (int kk = 0; kk < 2; ++kk)
      boff[n][kk] = row * 128 + (((kk * 4 + hi) ^ (row & 7)) << 4);
  }

  const int waveB = wv * 1024;
  const int nkt = K >> 6;

  gload_lds16(pA0,   AsB + waveB);
  gload_lds16(pB[0], BsB + waveB);
  gload_lds16(pB[1], BsB + 8192 + waveB);
  __syncthreads();

  int cur = 0;
  for (int kt = 0; kt < nkt; ++kt) {
    const int curA = cur * 8192, curB = cur * 16384;
    if (kt + 1 < nkt) {
      const int ke = (kt + 1) * 64;
      gload_lds16(pA0 + ke,   AsB + (curA ^ 8192) + waveB);
      gload_lds16(pB[0] + ke, BsB + (curB ^ 16384) + waveB);
      gload_lds16(pB[1] + ke, BsB + (curB ^ 16384) + 8192 + waveB);
    }

    bf16x8 a[2][2], b[2][2];
#pragma unroll
    for (int m = 0; m < 2; ++m)
#pragma unroll
      for (int kk = 0; kk < 2; ++kk)
        a[m][kk] = *(const bf16x8*)(AsB + curA + aoff[m][kk]);
#pragma unroll
    for (int n = 0; n < 2; ++n)
#pragma unroll
      for (int kk = 0; kk < 2; ++kk)
        b[n][kk] = *(const bf16x8*)(BsB + curB + boff[n][kk]);

#pragma unroll
    for (int kk = 0; kk < 2; ++kk)
#pragma unroll
      for (int m = 0; m < 2; ++m)
#pragma unroll
        for (int n = 0; n < 2; ++n)
          acc[m][n] = __builtin_amdgcn_mfma_f32_16x16x32_bf16(a[m][kk], b[n][kk], acc[m][n], 0, 0, 0);

    if (kt + 1 < nkt) {
      __syncthreads();
      cur ^= 1;
    }
  }

  const int N = Lr.N;
#pragma unroll
  for (int m = 0; m < 2; ++m) {
#pragma unroll
    for (int n = 0; n < 2; ++n) {
#pragma unroll
      for (int r = 0; r < 4; ++r) {
        const int row = rowBase + wrM * 32 + m * 16 + hi * 4 + r;
        const int col = colBase + wcN * 32 + n * 16 + lo;
        const float v = acc[m][n][r];
        const size_t iN = (size_t)row * N + col;
        const size_t iO = (size_t)row * Lr.ostride + col;
        if (Lr.mode == 0) {
          const float mu = Lr.X[iN];
          const float t  = tanhf(v);
          const float e  = mu - t;
          Lr.O1[iO] = e;
          Lr.O2[iN] = __float2bfloat16(e * (1.0f - t * t));
        } else if (Lr.mode == 1) {
          const float e = Lr.X[iN] - v;
          Lr.O1[iO] = e;
          Lr.O2[iN] = __float2bfloat16(e);
        }
      }
    }
  }
}

// ======================= prep kernels =======================
__global__ void prep_all(const float* __restrict__ W, bf16_t* __restrict__ WTb,
                         uint8_t* __restrict__ W8, uint8_t* __restrict__ WT8,
                         int R, int C) {
  __shared__ float t[64][65];
  const int tx = threadIdx.x, ty = threadIdx.y;  // (64,4)
  const int c0 = blockIdx.x * 64, r0 = blockIdx.y * 64;
  for (int rr = ty; rr < 64; rr += 4) {
    const float v = W[(size_t)(r0 + rr) * C + c0 + tx];
    W8[(size_t)(r0 + rr) * C + c0 + tx] = f2fp8(v * S8);
    t[rr][tx] = v;
  }
  __syncthreads();
  for (int rr = ty; rr < 64; rr += 4) {
    const float v = t[tx][rr];
    WTb[(size_t)(c0 + rr) * R + r0 + tx] = __float2bfloat16(v);
    WT8[(size_t)(c0 + rr) * R + r0 + tx] = f2fp8(v * S8);
  }
}

__global__ void copy_cast3(const float* __restrict__ in, float* __restrict__ of,
                           uint8_t* __restrict__ o8, bf16_t* __restrict__ ob, int n) {
  const int i = blockIdx.x * blockDim.x + threadIdx.x;
  if (i < n) {
    const float v = in[i];
    of[i] = v;
    o8[i] = f2fp8(v * S8);
    ob[i] = __float2bfloat16(v);
  }
}

__global__ void copy_e0(const float* __restrict__ mu0, float* __restrict__ out) {
  const int i = blockIdx.x * blockDim.x + threadIdx.x;
  if (i < 512 * 1024) {
    const int b = i >> 10, j = i & 1023;
    out[(size_t)b * 12288 + j] = mu0[i];
  }
}

extern "C" void kernel_launch(void* const* d_in, const int* in_sizes, int n_in,
                              void* d_out, int out_size, void* d_ws, size_t ws_size,
                              hipStream_t stream) {
  const float* img  = (const float*)d_in[0];
  const float* mu0i = (const float*)d_in[1];
  const float* mu1i = (const float*)d_in[2];
  const float* mu2i = (const float*)d_in[3];
  const float* W0   = (const float*)d_in[4];
  const float* W1   = (const float*)d_in[5];
  const float* W2   = (const float*)d_in[6];
  float* out = (float*)d_out;
  const int n_iters = 20;  // fixed by setup_inputs

  // ---- workspace carve ----
  char* p = (char*)d_ws;
  auto alloc = [&](size_t bytes) -> char* {
    char* r = p;
    p += (bytes + 255) & ~(size_t)255;
    return r;
  };
  bf16_t* WT0 = (bf16_t*)alloc((size_t)4096 * 1024 * 2);
  bf16_t* WT1 = (bf16_t*)alloc((size_t)4096 * 4096 * 2);
  bf16_t* WT2 = (bf16_t*)alloc((size_t)3072 * 4096 * 2);
  uint8_t* W80  = (uint8_t*)alloc((size_t)1024 * 4096);
  uint8_t* W81  = (uint8_t*)alloc((size_t)4096 * 4096);
  uint8_t* W82  = (uint8_t*)alloc((size_t)4096 * 3072);
  uint8_t* WT80 = (uint8_t*)alloc((size_t)4096 * 1024);
  uint8_t* WT81 = (uint8_t*)alloc((size_t)4096 * 4096);
  uint8_t* WT82 = (uint8_t*)alloc((size_t)3072 * 4096);
  float*   mu0 = (float*)alloc((size_t)512 * 1024 * 4);
  float*   mu1 = (float*)alloc((size_t)512 * 4096 * 4);
  float*   mu2 = (float*)alloc((size_t)512 * 4096 * 4);
  uint8_t* m80 = (uint8_t*)alloc((size_t)512 * 1024);
  uint8_t* m81 = (uint8_t*)alloc((size_t)512 * 4096);
  uint8_t* m82 = (uint8_t*)alloc((size_t)512 * 4096);
  bf16_t*  mb0 = (bf16_t*)alloc((size_t)512 * 1024 * 2);
  bf16_t*  mb1 = (bf16_t*)alloc((size_t)512 * 4096 * 2);
  bf16_t*  mb2 = (bf16_t*)alloc((size_t)512 * 4096 * 2);
  float*   e1  = (float*)alloc((size_t)512 * 4096 * 4);
  float*   e2  = (float*)alloc((size_t)512 * 4096 * 4);
  float*   e3  = (float*)alloc((size_t)512 * 3072 * 4);
  uint8_t* G80 = (uint8_t*)alloc((size_t)512 * 4096);
  uint8_t* G81 = (uint8_t*)alloc((size_t)512 * 4096);
  uint8_t* G82 = (uint8_t*)alloc((size_t)512 * 3072);
  bf16_t*  Gb0 = (bf16_t*)alloc((size_t)512 * 4096 * 2);
  bf16_t*  Gb1 = (bf16_t*)alloc((size_t)512 * 4096 * 2);
  bf16_t*  Gb2 = (bf16_t*)alloc((size_t)512 * 3072 * 2);
  (void)ws_size;

  // ---- prep ----
  dim3 tb(64, 4);
  prep_all<<<dim3(4096 / 64, 1024 / 64), tb, 0, stream>>>(W0, WT0, W80, WT80, 1024, 4096);
  prep_all<<<dim3(4096 / 64, 4096 / 64), tb, 0, stream>>>(W1, WT1, W81, WT81, 4096, 4096);
  prep_all<<<dim3(3072 / 64, 4096 / 64), tb, 0, stream>>>(W2, WT2, W82, WT82, 4096, 3072);
  copy_cast3<<<(512 * 1024 + 255) / 256, 256, 0, stream>>>(mu0i, mu0, m80, mb0, 512 * 1024);
  copy_cast3<<<(512 * 4096 + 255) / 256, 256, 0, stream>>>(mu1i, mu1, m81, mb1, 512 * 4096);
  copy_cast3<<<(512 * 4096 + 255) / 256, 256, 0, stream>>>(mu2i, mu2, m82, mb2, 512 * 4096);

  const Seg SENT = { 1 << 30, 0, 0, 1 };

  // ---- fp8 forward: 128^2 tiles. Jobs: L0 4x32=128 (8 steps),
  // L1 4x32=128 (32), L2 4x24=96 (32). Order for round-robin id->CU:
  // ids[0,96)=L2, [96,224)=L1, [224,256)=L0 tm0, [256,352)=L0 tm1-3.
  // CU<96: L2+L0=40; [96,224): L1=32; [224,256): L0=8. Makespan 40.
  GemmArgs8 fa;
  fa.L[0] = { m80, WT80, mu1, nullptr, e1, G80, nullptr, 1024, 4096, 0 };
  fa.L[1] = { m81, WT81, mu2, nullptr, e2, G81, nullptr, 4096, 4096, 0 };
  fa.L[2] = { m82, WT82, img, nullptr, e3, G82, nullptr, 4096, 3072, 1 };
  fa.seg[0] = { 0,   2, 0, 24 };   // L2: 96
  fa.seg[1] = { 96,  1, 0, 32 };   // L1: 128
  fa.seg[2] = { 224, 0, 0, 32 };   // L0 tm0: 32
  fa.seg[3] = { 256, 0, 1, 32 };   // L0 tm1-3: 96
  fa.seg[4] = SENT; fa.seg[5] = SENT; fa.seg[6] = SENT; fa.seg[7] = SENT;
  const int fwdBlocks = 352;

  // ---- fp8 backward: Jobs: L0 4x8=32 (32 steps), L1 128 (32),
  // L2 4x32=128 (24). Order: ids[0,32)=L2 tm0, [32,160)=L1, [160,192)=L0,
  // [192,256)=L2 tm1-2, [256,288)=L2 tm3.
  // CU<32: L2+L2=48; [32,160): L1=32; [160,192): L0=32; [192,256): L2=24.
  GemmArgs8 ba;
  ba.L[0] = { G80, W80, mu0, nullptr, mu0, m80, mb0, 4096, 1024, 2 };
  ba.L[1] = { G81, W81, mu1, e1,      mu1, m81, mb1, 4096, 4096, 3 };
  ba.L[2] = { G82, W82, mu2, e2,      mu2, m82, mb2, 3072, 4096, 3 };
  ba.seg[0] = { 0,   2, 0, 32 };   // L2 tm0: 32
  ba.seg[1] = { 32,  1, 0, 32 };   // L1: 128
  ba.seg[2] = { 160, 0, 0, 8 };    // L0: 32
  ba.seg[3] = { 192, 2, 1, 32 };   // L2 tm1-2: 64
  ba.seg[4] = { 256, 2, 3, 32 };   // L2 tm3: 32
  ba.seg[5] = SENT; ba.seg[6] = SENT; ba.seg[7] = SENT;
  const int bwdBlocks = 288;

  // ---- bf16 final pass (R16 layout, proven) ----
  GemmArgs faF;
  faF.L[0] = { mb0, WT0, mu1, nullptr, out + 1024, Gb0, 1024, 4096, 12288, 0 };
  faF.L[1] = { mb1, WT1, mu2, nullptr, out + 5120, Gb1, 4096, 4096, 12288, 0 };
  faF.L[2] = { mb2, WT2, img, nullptr, out + 9216, Gb2, 4096, 3072, 12288, 1 };
  faF.seg[0] = { 0,   0, 0, 32 };
  faF.seg[1] = { 256, 1, 0, 32 };
  faF.seg[2] = { 512, 2, 0, 24 };
  faF.seg[3] = SENT; faF.seg[4] = SENT; faF.seg[5] = SENT;
  faF.seg[6] = SENT; faF.seg[7] = SENT;

  // ---- iterate ----
  for (int it = 0; it < n_iters; ++it) {
    gemm_fp8<<<fwdBlocks, 1024, 0, stream>>>(fa);
    gemm_fp8<<<bwdBlocks, 1024, 0, stream>>>(ba);
  }
  gemm_bf16<<<704, 512, 0, stream>>>(faF);
  copy_e0<<<(512 * 1024 + 255) / 256, 256, 0, stream>>>(mu0, out);
}